// Round 12
// baseline (276.824 us; speedup 1.0000x reference)
//
#include <hip/hip_runtime.h>
#include <hip/hip_bf16.h>
#include <math.h>

typedef __bf16 bf16;
typedef __bf16 bf16x4 __attribute__((ext_vector_type(4)));
typedef __bf16 bf16x8 __attribute__((ext_vector_type(8)));
typedef float floatx4 __attribute__((ext_vector_type(4)));
typedef short short4v __attribute__((ext_vector_type(4)));

#define S_LEN 4096
#define DM 1024
#define NH 16
#define HD 64

#define GM 4096
#define GN 1024
#define GK 1024
#define FST 68     // flash LDS row stride (r0-exact)

// softmax scale folded into Q at projection: 1/sqrt(64) * log2(e)
#define QSCALE 0.18033688011112042f

// async global->LDS, 16B per lane; lds base wave-uniform (m97/m104)
#define GLDS16(gp, lp) __builtin_amdgcn_global_load_lds( \
    (const __attribute__((address_space(1))) void*)(gp), \
    (__attribute__((address_space(3))) void*)(lp), 16, 0, 0)

// ---------------------------------------------------------------------------
// fp32 -> bf16: x (4M) + wq/wk/wv/wo (1M each) into contiguous ws.
// ---------------------------------------------------------------------------
__global__ void cvt_bf16(const float* __restrict__ x,  const float* __restrict__ wq,
                         const float* __restrict__ wk, const float* __restrict__ wv,
                         const float* __restrict__ wo, bf16* __restrict__ dst)
{
    size_t i4 = ((size_t)blockIdx.x * 256 + threadIdx.x) * 4;   // 8M elems total
    const float* src; size_t off;
    const size_t M1 = (size_t)1 << 20;
    if      (i4 < 4 * M1) { src = x;  off = i4;          }
    else if (i4 < 5 * M1) { src = wq; off = i4 - 4 * M1; }
    else if (i4 < 6 * M1) { src = wk; off = i4 - 5 * M1; }
    else if (i4 < 7 * M1) { src = wv; off = i4 - 6 * M1; }
    else                  { src = wo; off = i4 - 7 * M1; }
    float4 v = *(const float4*)(src + off);
    bf16x4 o = { (bf16)v.x, (bf16)v.y, (bf16)v.z, (bf16)v.w };
    *(bf16x4*)(&dst[i4]) = o;
}

// ---------------------------------------------------------------------------
// Fused QKV GEMM (r11-exact): 1buf LDS (24KB, 6 blocks/CU) + T2 swizzle +
// T1 XCD-chunked swizzle (measured neutral, kept — harmless permutation).
// Epilogue per z: z=0 Q: RoPE * QSCALE; z=1 K: RoPE; z=2 V: transposed store.
// ---------------------------------------------------------------------------
__launch_bounds__(256)
__global__ void gemm_qkv(const bf16* __restrict__ A,
                         const bf16* __restrict__ B0, const bf16* __restrict__ B1,
                         const bf16* __restrict__ B2,
                         const float* __restrict__ cosp, const float* __restrict__ sinp,
                         bf16* __restrict__ Qw, bf16* __restrict__ Kw,
                         bf16* __restrict__ VTw)
{
    const int bid = blockIdx.x;                 // 0..1535, 1-D launch
    const int swz = (bid & 7) * 192 + (bid >> 3);
    const int bz  = swz >> 9;                   // slice: 512 blocks each
    const int rem = swz & 511;
    const int m0  = (rem >> 3) * 64;            // 64 M-tiles (y)
    const int n0  = (rem & 7) * 128;            // 8 N-tiles (x)
    const bf16* __restrict__ B = (bz == 0) ? B0 : (bz == 1 ? B1 : B2);

    const int tid  = threadIdx.x;
    const int wave = tid >> 6;
    const int lane = tid & 63;
    const int wm   = (wave >> 1) * 32;
    const int wn   = (wave & 1) * 64;
    const int lrow = lane >> 4;
    const int lcol = lane & 15;

    __shared__ __align__(16) bf16 As[64 * 64];
    __shared__ __align__(16) bf16 Bs[128 * 64];

    floatx4 acc[2][4];
    #pragma unroll
    for (int i = 0; i < 2; i++)
        #pragma unroll
        for (int j = 0; j < 4; j++) acc[i][j] = (floatx4){0.f, 0.f, 0.f, 0.f};

    // pre-swizzled global source chunk (write side of T2)
    const int swc = (((lane & 7) ^ ((lane >> 3) & 7))) * 8;
    const bf16* ga0 = A + (size_t)(m0 + wave * 16 + (lane >> 3)) * GK + swc;
    const bf16* gb0 = B + (size_t)(n0 + wave * 32 + (lane >> 3)) * GK + swc;
    bf16* la = &As[(wave * 16) * 64];
    bf16* lb = &Bs[(wave * 32) * 64];
    // swizzled read offsets (read side of T2), lane-constant
    const int kof0 = ((0 + lrow) ^ (lcol & 7)) * 8;
    const int kof1 = ((4 + lrow) ^ (lcol & 7)) * 8;

    for (int kt = 0; kt < GK; kt += 64) {
        #pragma unroll
        for (int i = 0; i < 2; i++)
            GLDS16(ga0 + kt + (size_t)i * 8 * GK, la + i * 8 * 64);
        #pragma unroll
        for (int i = 0; i < 4; i++)
            GLDS16(gb0 + kt + (size_t)i * 8 * GK, lb + i * 8 * 64);
        __syncthreads();
        #pragma unroll
        for (int ks = 0; ks < 2; ks++) {
            const int ko = ks ? kof1 : kof0;
            bf16x8 af[2], bfr[4];
            #pragma unroll
            for (int t = 0; t < 2; t++)
                af[t]  = *(const bf16x8*)(&As[(wm + t * 16 + lcol) * 64 + ko]);
            #pragma unroll
            for (int t = 0; t < 4; t++)
                bfr[t] = *(const bf16x8*)(&Bs[(wn + t * 16 + lcol) * 64 + ko]);
            #pragma unroll
            for (int mt = 0; mt < 2; mt++)
                #pragma unroll
                for (int nt = 0; nt < 4; nt++)
                    acc[mt][nt] = __builtin_amdgcn_mfma_f32_16x16x32_bf16(af[mt], bfr[nt], acc[mt][nt], 0, 0, 0);
        }
        __syncthreads();
    }

    if (bz < 2) {
        bf16* __restrict__ C = bz ? Kw : Qw;
        const float qs = (bz == 0) ? QSCALE : 1.0f;
        const bool odd = (lcol & 1);
        #pragma unroll
        for (int mt = 0; mt < 2; mt++)
            #pragma unroll
            for (int nt = 0; nt < 4; nt++) {
                int i = (nt * 16 + lcol) >> 1;   // freq index 0..31 (cols repeat per head)
                #pragma unroll
                for (int r = 0; r < 4; r++) {
                    float v  = acc[mt][nt][r];
                    float pv = __shfl_xor(v, 1, 64);
                    int s = m0 + wm + mt * 16 + lrow * 4 + r;
                    float c  = cosp[s * 32 + i];
                    float sn = sinp[s * 32 + i];
                    float ov = odd ? (pv * sn + v * c) : (v * c - pv * sn);
                    C[(size_t)s * GN + n0 + wn + nt * 16 + lcol] = (bf16)(ov * qs);
                }
            }
    } else {
        #pragma unroll
        for (int mt = 0; mt < 2; mt++)
            #pragma unroll
            for (int nt = 0; nt < 4; nt++) {
                int col = n0 + wn + nt * 16 + lcol;
                int s   = m0 + wm + mt * 16 + lrow * 4;
                bf16x4 ov = { (bf16)acc[mt][nt][0], (bf16)acc[mt][nt][1],
                              (bf16)acc[mt][nt][2], (bf16)acc[mt][nt][3] };
                *(bf16x4*)(&VTw[(size_t)col * S_LEN + s]) = ov;
            }
    }
}

// ---------------------------------------------------------------------------
// Flash attention r22: r10/r11 loop + ISOLATED s_setprio around the MFMA
// clusters (T5). Regime check (m190/m191): setprio is null on lockstep
// GEMM waves but +4-7% on attn where co-resident blocks sit at DIFFERENT
// phases — true here (per-block trip counts 16..32, 4 blocks/CU never in
// phase). The earlier r3 negative was confounded (bundled with swizzle +
// 3-way split); this is the clean single-variable test.
// ---------------------------------------------------------------------------
__launch_bounds__(256, 4)
__global__ void flash_attn(const bf16* __restrict__ Q, const bf16* __restrict__ K,
                           const bf16* __restrict__ VT,
                           float* __restrict__ O0, float* __restrict__ O1,
                           float* __restrict__ L0, float* __restrict__ L1)
{
    const int h    = blockIdx.y;
    const int pi0  = blockIdx.x >> 1;
    const int pi   = ((h >> 2) & 1) ? (31 - pi0) : pi0;
    const int p    = blockIdx.x & 1;
    const int tid  = threadIdx.x;
    const int wave = tid >> 6;
    const int lane = tid & 63;
    const int lrow = lane >> 4;
    const int lcol = lane & 15;

    const int qtA = pi;
    const int qtB = 63 - pi;

    float* __restrict__ Op = p ? O1 : O0;
    float* __restrict__ Lp = p ? L1 : L0;

    __shared__ __align__(16) bf16 Ks[2][64 * FST];
    __shared__ __align__(16) bf16 Vs[2][64 * FST];

    const int q0A = qtA * 64 + wave * 16;
    const int q0B = qtB * 64 + wave * 16;

    const bf16* qpA = Q + (size_t)(q0A + lcol) * DM + h * HD;
    const bf16* qpB = Q + (size_t)(q0B + lcol) * DM + h * HD;
    bf16x8 qfA[2], qfB[2];
    qfA[0] = *(const bf16x8*)(qpA + 0 + lrow * 8);
    qfA[1] = *(const bf16x8*)(qpA + 32 + lrow * 8);
    qfB[0] = *(const bf16x8*)(qpB + 0 + lrow * 8);
    qfB[1] = *(const bf16x8*)(qpB + 32 + lrow * 8);

    float lA = 0.f, lB = 0.f;
    floatx4 oaccA[4], oaccB[4];
    #pragma unroll
    for (int nt = 0; nt < 4; nt++) {
        oaccA[nt] = (floatx4){0.f, 0.f, 0.f, 0.f};
        oaccB[nt] = (floatx4){0.f, 0.f, 0.f, 0.f};
    }

    const int  srow = tid >> 3;
    const int  sch  = (tid & 7) * 8;
    const bf16* kp  = K  + (size_t)srow * DM + h * HD + sch;
    const bf16* vp  = VT + (size_t)(h * HD + srow) * S_LEN + sch;
    const int  wof  = srow * FST + sch;

    {
        size_t ko = (size_t)p * 64 * DM;
        size_t vo = (size_t)p * 64;
        uint4 a = *(const uint4*)(kp + ko);
        uint4 b = *(const uint4*)(kp + ko + (size_t)32 * DM);
        uint4 c = *(const uint4*)(vp + vo);
        uint4 d = *(const uint4*)(vp + vo + (size_t)32 * S_LEN);
        *(uint4*)(&Ks[0][wof])            = a;
        *(uint4*)(&Ks[0][wof + 32 * FST]) = b;
        *(uint4*)(&Vs[0][wof])            = c;
        *(uint4*)(&Vs[0][wof + 32 * FST]) = d;
    }
    __syncthreads();

    uint4 kr0, kr1, vr0, vr1;
    for (int t = p; t <= qtB; t += 2) {
        const int  cur  = ((t - p) >> 1) & 1;
        const bool more = (t + 2 <= qtB);
        const bool actA = (t <= qtA);

        if (more) {
            size_t ko = (size_t)(t + 2) * 64 * DM;
            size_t vo = (size_t)(t + 2) * 64;
            kr0 = *(const uint4*)(kp + ko);
            kr1 = *(const uint4*)(kp + ko + (size_t)32 * DM);
            vr0 = *(const uint4*)(vp + vo);
            vr1 = *(const uint4*)(vp + vo + (size_t)32 * S_LEN);
        }

        short4v pbA[4], pbB[4];
        const bool diagA = (t == qtA);
        const bool diagB = (t == qtB);
        #pragma unroll
        for (int nt = 0; nt < 4; nt++) {
            floatx4 zB = (floatx4){0.f, 0.f, 0.f, 0.f};
            floatx4 zA = (floatx4){0.f, 0.f, 0.f, 0.f};
            __builtin_amdgcn_s_setprio(1);
            #pragma unroll
            for (int ks = 0; ks < 2; ks++) {
                bf16x8 kf = *(const bf16x8*)(&Ks[cur][(nt * 16 + lcol) * FST + ks * 32 + lrow * 8]);
                zB = __builtin_amdgcn_mfma_f32_16x16x32_bf16(kf, qfB[ks], zB, 0, 0, 0);
                if (actA)
                    zA = __builtin_amdgcn_mfma_f32_16x16x32_bf16(kf, qfA[ks], zA, 0, 0, 0);
            }
            __builtin_amdgcn_s_setprio(0);
            if (diagB) {
                #pragma unroll
                for (int r = 0; r < 4; r++) {
                    int kg = t * 64 + nt * 16 + lrow * 4 + r;
                    float pr = exp2f(zB[r]);
                    if (kg > q0B + lcol) pr = 0.f;
                    zB[r] = pr; lB += pr;
                }
            } else {
                #pragma unroll
                for (int r = 0; r < 4; r++) {
                    float pr = exp2f(zB[r]);
                    zB[r] = pr; lB += pr;
                }
            }
            bf16x4 pvB = { (bf16)zB[0], (bf16)zB[1], (bf16)zB[2], (bf16)zB[3] };
            pbB[nt] = __builtin_bit_cast(short4v, pvB);
            if (actA) {
                if (diagA) {
                    #pragma unroll
                    for (int r = 0; r < 4; r++) {
                        int kg = t * 64 + nt * 16 + lrow * 4 + r;
                        float pr = exp2f(zA[r]);
                        if (kg > q0A + lcol) pr = 0.f;
                        zA[r] = pr; lA += pr;
                    }
                } else {
                    #pragma unroll
                    for (int r = 0; r < 4; r++) {
                        float pr = exp2f(zA[r]);
                        zA[r] = pr; lA += pr;
                    }
                }
                bf16x4 pvA = { (bf16)zA[0], (bf16)zA[1], (bf16)zA[2], (bf16)zA[3] };
                pbA[nt] = __builtin_bit_cast(short4v, pvA);
            }
        }

        __builtin_amdgcn_s_setprio(1);
        #pragma unroll
        for (int nt = 0; nt < 4; nt++)
            #pragma unroll
            for (int kt = 0; kt < 4; kt++) {
                bf16x4 va = *(const bf16x4*)(&Vs[cur][(nt * 16 + lcol) * FST + kt * 16 + lrow * 4]);
                short4v vas = __builtin_bit_cast(short4v, va);
                oaccB[nt] = __builtin_amdgcn_mfma_f32_16x16x16bf16_1k(vas, pbB[kt], oaccB[nt], 0, 0, 0);
                if (actA)
                    oaccA[nt] = __builtin_amdgcn_mfma_f32_16x16x16bf16_1k(vas, pbA[kt], oaccA[nt], 0, 0, 0);
            }
        __builtin_amdgcn_s_setprio(0);

        if (more) {
            int nxt = cur ^ 1;
            *(uint4*)(&Ks[nxt][wof])            = kr0;
            *(uint4*)(&Ks[nxt][wof + 32 * FST]) = kr1;
            *(uint4*)(&Vs[nxt][wof])            = vr0;
            *(uint4*)(&Vs[nxt][wof + 32 * FST]) = vr1;
        }
        __syncthreads();
    }

    lA += __shfl_xor(lA, 16, 64);
    lA += __shfl_xor(lA, 32, 64);
    lB += __shfl_xor(lB, 16, 64);
    lB += __shfl_xor(lB, 32, 64);
    if (lrow == 0) {
        Lp[h * S_LEN + q0A + lcol] = lA;
        Lp[h * S_LEN + q0B + lcol] = lB;
    }
    #pragma unroll
    for (int nt = 0; nt < 4; nt++) {
        *(floatx4*)(&Op[(size_t)(q0A + lcol) * DM + h * HD + nt * 16 + lrow * 4]) = oaccA[nt];
        *(floatx4*)(&Op[(size_t)(q0B + lcol) * DM + h * HD + nt * 16 + lrow * 4]) = oaccB[nt];
    }
}

// ---------------------------------------------------------------------------
// Combine: Aw = (O0 + O1) / (l0 + l1), fp32 -> bf16.
// ---------------------------------------------------------------------------
__global__ void combine_kernel(const float* __restrict__ O0, const float* __restrict__ O1,
                               const float* __restrict__ L0, const float* __restrict__ L1,
                               bf16* __restrict__ Aw)
{
    int i4 = (blockIdx.x * 256 + threadIdx.x) * 4;   // 4M elems
    int q = i4 >> 10;
    int c = i4 & 1023;
    int h = c >> 6;
    float rl = 1.f / (L0[h * S_LEN + q] + L1[h * S_LEN + q]);
    float4 a = *(const float4*)(O0 + i4);
    float4 b = *(const float4*)(O1 + i4);
    bf16x4 o = { (bf16)((a.x + b.x) * rl), (bf16)((a.y + b.y) * rl),
                 (bf16)((a.z + b.z) * rl), (bf16)((a.w + b.w) * rl) };
    *(bf16x4*)(&Aw[i4]) = o;
}

// ---------------------------------------------------------------------------
// Output projection (r11-exact): dbuf + T2 swizzle + XCD-chunk.
// ---------------------------------------------------------------------------
__launch_bounds__(256)
__global__ void gemm_out(const bf16* __restrict__ A, const bf16* __restrict__ B,
                         float* __restrict__ out)
{
    const int bid = blockIdx.x;                 // 0..511, 1-D launch
    const int swz = (bid & 7) * 64 + (bid >> 3);
    const int m0  = (swz >> 3) * 64;
    const int n0  = (swz & 7) * 128;

    const int tid  = threadIdx.x;
    const int wave = tid >> 6;
    const int lane = tid & 63;
    const int wm   = (wave >> 1) * 32;
    const int wn   = (wave & 1) * 64;
    const int lrow = lane >> 4;
    const int lcol = lane & 15;

    __shared__ __align__(16) bf16 As[2][64 * 64];
    __shared__ __align__(16) bf16 Bs[2][128 * 64];

    floatx4 acc[2][4];
    #pragma unroll
    for (int i = 0; i < 2; i++)
        #pragma unroll
        for (int j = 0; j < 4; j++) acc[i][j] = (floatx4){0.f, 0.f, 0.f, 0.f};

    const int swc = (((lane & 7) ^ ((lane >> 3) & 7))) * 8;
    const bf16* ga0 = A + (size_t)(m0 + wave * 16 + (lane >> 3)) * GK + swc;
    const bf16* gb0 = B + (size_t)(n0 + wave * 32 + (lane >> 3)) * GK + swc;
    const int kof0 = ((0 + lrow) ^ (lcol & 7)) * 8;
    const int kof1 = ((4 + lrow) ^ (lcol & 7)) * 8;

    #pragma unroll
    for (int i = 0; i < 2; i++)
        GLDS16(ga0 + (size_t)i * 8 * GK, &As[0][(wave * 16 + i * 8) * 64]);
    #pragma unroll
    for (int i = 0; i < 4; i++)
        GLDS16(gb0 + (size_t)i * 8 * GK, &Bs[0][(wave * 32 + i * 8) * 64]);
    __syncthreads();

    int cur = 0;
    for (int kt = 0; kt < GK; kt += 64) {
        if (kt + 64 < GK) {
            #pragma unroll
            for (int i = 0; i < 2; i++)
                GLDS16(ga0 + kt + 64 + (size_t)i * 8 * GK, &As[cur ^ 1][(wave * 16 + i * 8) * 64]);
            #pragma unroll
            for (int i = 0; i < 4; i++)
                GLDS16(gb0 + kt + 64 + (size_t)i * 8 * GK, &Bs[cur ^ 1][(wave * 32 + i * 8) * 64]);
        }
        #pragma unroll
        for (int ks = 0; ks < 2; ks++) {
            const int ko = ks ? kof1 : kof0;
            bf16x8 af[2], bfr[4];
            #pragma unroll
            for (int t = 0; t < 2; t++)
                af[t]  = *(const bf16x8*)(&As[cur][(wm + t * 16 + lcol) * 64 + ko]);
            #pragma unroll
            for (int t = 0; t < 4; t++)
                bfr[t] = *(const bf16x8*)(&Bs[cur][(wn + t * 16 + lcol) * 64 + ko]);
            #pragma unroll
            for (int mt = 0; mt < 2; mt++)
                #pragma unroll
                for (int nt = 0; nt < 4; nt++)
                    acc[mt][nt] = __builtin_amdgcn_mfma_f32_16x16x32_bf16(af[mt], bfr[nt], acc[mt][nt], 0, 0, 0);
        }
        __syncthreads();
        cur ^= 1;
    }

    #pragma unroll
    for (int mt = 0; mt < 2; mt++)
        #pragma unroll
        for (int nt = 0; nt < 4; nt++)
            #pragma unroll
            for (int r = 0; r < 4; r++) {
                int row = m0 + wm + mt * 16 + lrow * 4 + r;
                int col = n0 + wn + nt * 16 + lcol;
                out[(size_t)row * GN + col] = acc[mt][nt][r];
            }
}

// ---------------------------------------------------------------------------
extern "C" void kernel_launch(void* const* d_in, const int* in_sizes, int n_in,
                              void* d_out, int out_size, void* d_ws, size_t ws_size,
                              hipStream_t stream) {
    const float* x    = (const float*)d_in[0];
    const float* cosp = (const float*)d_in[1];
    const float* sinp = (const float*)d_in[2];
    const float* wq   = (const float*)d_in[4];
    const float* wk   = (const float*)d_in[5];
    const float* wv   = (const float*)d_in[6];
    const float* wo   = (const float*)d_in[7];
    float* out = (float*)d_out;

    const size_t SD = (size_t)S_LEN * DM;   // 4M elems
    const size_t DD = (size_t)DM * DM;      // 1M elems
    bf16* xb  = (bf16*)d_ws;                // 4M bf16
    bf16* wqb = xb + SD;
    bf16* wkb = wqb + DD;
    bf16* wvb = wkb + DD;
    bf16* wob = wvb + DD;
    bf16* Qw  = wob + DD;                   // 4M bf16 each
    bf16* Kw  = Qw + SD;
    bf16* VTw = Kw + SD;
    bf16* Aw  = VTw + SD;
    float* O0f = (float*)(Aw + SD);         // 4M fp32 each
    float* O1f = O0f + SD;
    float* L0f = O1f + SD;                  // 64K fp32 each
    float* L1f = L0f + (size_t)S_LEN * NH;

    // 1) fp32 -> bf16 (x + 4 weights)
    cvt_bf16<<<8192, 256, 0, stream>>>(x, wq, wk, wv, wo, xb);
    // 2) QKV projections + RoPE(+scale) + V-transpose (1buf+swz, XCD-chunked)
    gemm_qkv<<<1536, 256, 0, stream>>>(
        xb, wqb, wkb, wvb, cosp, sinp, Qw, Kw, VTw);
    // 3) flash attention (parity-split partials + isolated setprio)
    flash_attn<<<dim3(64, NH), 256, 0, stream>>>(Qw, Kw, VTw, O0f, O1f, L0f, L1f);
    // 4) combine partials -> bf16 Aw
    combine_kernel<<<S_LEN * DM / 1024, 256, 0, stream>>>(O0f, O1f, L0f, L1f, Aw);
    // 5) output projection (dbuf+swz, XCD-chunked)
    gemm_out<<<512, 256, 0, stream>>>(Aw, wob, out);
}

// Round 13
// 272.421 us; speedup vs baseline: 1.0162x; 1.0162x over previous
//
#include <hip/hip_runtime.h>
#include <hip/hip_bf16.h>
#include <math.h>

typedef __bf16 bf16;
typedef __bf16 bf16x4 __attribute__((ext_vector_type(4)));
typedef __bf16 bf16x8 __attribute__((ext_vector_type(8)));
typedef float floatx4 __attribute__((ext_vector_type(4)));
typedef short short4v __attribute__((ext_vector_type(4)));

#define S_LEN 4096
#define DM 1024
#define NH 16
#define HD 64

#define GM 4096
#define GN 1024
#define GK 1024
#define FST 68     // flash LDS row stride (r0-exact)

// softmax scale folded into Q at projection: 1/sqrt(64) * log2(e)
#define QSCALE 0.18033688011112042f

// async global->LDS, 16B per lane; lds base wave-uniform (m97/m104)
#define GLDS16(gp, lp) __builtin_amdgcn_global_load_lds( \
    (const __attribute__((address_space(1))) void*)(gp), \
    (__attribute__((address_space(3))) void*)(lp), 16, 0, 0)

// ---------------------------------------------------------------------------
// fp32 -> bf16: x (4M) + wq/wk/wv/wo (1M each) into contiguous ws.
// ---------------------------------------------------------------------------
__global__ void cvt_bf16(const float* __restrict__ x,  const float* __restrict__ wq,
                         const float* __restrict__ wk, const float* __restrict__ wv,
                         const float* __restrict__ wo, bf16* __restrict__ dst)
{
    size_t i4 = ((size_t)blockIdx.x * 256 + threadIdx.x) * 4;   // 8M elems total
    const float* src; size_t off;
    const size_t M1 = (size_t)1 << 20;
    if      (i4 < 4 * M1) { src = x;  off = i4;          }
    else if (i4 < 5 * M1) { src = wq; off = i4 - 4 * M1; }
    else if (i4 < 6 * M1) { src = wk; off = i4 - 5 * M1; }
    else if (i4 < 7 * M1) { src = wv; off = i4 - 6 * M1; }
    else                  { src = wo; off = i4 - 7 * M1; }
    float4 v = *(const float4*)(src + off);
    bf16x4 o = { (bf16)v.x, (bf16)v.y, (bf16)v.z, (bf16)v.w };
    *(bf16x4*)(&dst[i4]) = o;
}

// ---------------------------------------------------------------------------
// Fused QKV GEMM (r11-exact): 1buf LDS (24KB, 6 blocks/CU) + T2 swizzle +
// T1 XCD-chunked swizzle.
// Epilogue per z: z=0 Q: RoPE * QSCALE; z=1 K: RoPE; z=2 V: transposed store.
// ---------------------------------------------------------------------------
__launch_bounds__(256)
__global__ void gemm_qkv(const bf16* __restrict__ A,
                         const bf16* __restrict__ B0, const bf16* __restrict__ B1,
                         const bf16* __restrict__ B2,
                         const float* __restrict__ cosp, const float* __restrict__ sinp,
                         bf16* __restrict__ Qw, bf16* __restrict__ Kw,
                         bf16* __restrict__ VTw)
{
    const int bid = blockIdx.x;                 // 0..1535, 1-D launch
    const int swz = (bid & 7) * 192 + (bid >> 3);
    const int bz  = swz >> 9;                   // slice: 512 blocks each
    const int rem = swz & 511;
    const int m0  = (rem >> 3) * 64;            // 64 M-tiles (y)
    const int n0  = (rem & 7) * 128;            // 8 N-tiles (x)
    const bf16* __restrict__ B = (bz == 0) ? B0 : (bz == 1 ? B1 : B2);

    const int tid  = threadIdx.x;
    const int wave = tid >> 6;
    const int lane = tid & 63;
    const int wm   = (wave >> 1) * 32;
    const int wn   = (wave & 1) * 64;
    const int lrow = lane >> 4;
    const int lcol = lane & 15;

    __shared__ __align__(16) bf16 As[64 * 64];
    __shared__ __align__(16) bf16 Bs[128 * 64];

    floatx4 acc[2][4];
    #pragma unroll
    for (int i = 0; i < 2; i++)
        #pragma unroll
        for (int j = 0; j < 4; j++) acc[i][j] = (floatx4){0.f, 0.f, 0.f, 0.f};

    // pre-swizzled global source chunk (write side of T2)
    const int swc = (((lane & 7) ^ ((lane >> 3) & 7))) * 8;
    const bf16* ga0 = A + (size_t)(m0 + wave * 16 + (lane >> 3)) * GK + swc;
    const bf16* gb0 = B + (size_t)(n0 + wave * 32 + (lane >> 3)) * GK + swc;
    bf16* la = &As[(wave * 16) * 64];
    bf16* lb = &Bs[(wave * 32) * 64];
    // swizzled read offsets (read side of T2), lane-constant
    const int kof0 = ((0 + lrow) ^ (lcol & 7)) * 8;
    const int kof1 = ((4 + lrow) ^ (lcol & 7)) * 8;

    for (int kt = 0; kt < GK; kt += 64) {
        #pragma unroll
        for (int i = 0; i < 2; i++)
            GLDS16(ga0 + kt + (size_t)i * 8 * GK, la + i * 8 * 64);
        #pragma unroll
        for (int i = 0; i < 4; i++)
            GLDS16(gb0 + kt + (size_t)i * 8 * GK, lb + i * 8 * 64);
        __syncthreads();
        #pragma unroll
        for (int ks = 0; ks < 2; ks++) {
            const int ko = ks ? kof1 : kof0;
            bf16x8 af[2], bfr[4];
            #pragma unroll
            for (int t = 0; t < 2; t++)
                af[t]  = *(const bf16x8*)(&As[(wm + t * 16 + lcol) * 64 + ko]);
            #pragma unroll
            for (int t = 0; t < 4; t++)
                bfr[t] = *(const bf16x8*)(&Bs[(wn + t * 16 + lcol) * 64 + ko]);
            #pragma unroll
            for (int mt = 0; mt < 2; mt++)
                #pragma unroll
                for (int nt = 0; nt < 4; nt++)
                    acc[mt][nt] = __builtin_amdgcn_mfma_f32_16x16x32_bf16(af[mt], bfr[nt], acc[mt][nt], 0, 0, 0);
        }
        __syncthreads();
    }

    if (bz < 2) {
        bf16* __restrict__ C = bz ? Kw : Qw;
        const float qs = (bz == 0) ? QSCALE : 1.0f;
        const bool odd = (lcol & 1);
        #pragma unroll
        for (int mt = 0; mt < 2; mt++)
            #pragma unroll
            for (int nt = 0; nt < 4; nt++) {
                int i = (nt * 16 + lcol) >> 1;   // freq index 0..31 (cols repeat per head)
                #pragma unroll
                for (int r = 0; r < 4; r++) {
                    float v  = acc[mt][nt][r];
                    float pv = __shfl_xor(v, 1, 64);
                    int s = m0 + wm + mt * 16 + lrow * 4 + r;
                    float c  = cosp[s * 32 + i];
                    float sn = sinp[s * 32 + i];
                    float ov = odd ? (pv * sn + v * c) : (v * c - pv * sn);
                    C[(size_t)s * GN + n0 + wn + nt * 16 + lcol] = (bf16)(ov * qs);
                }
            }
    } else {
        #pragma unroll
        for (int mt = 0; mt < 2; mt++)
            #pragma unroll
            for (int nt = 0; nt < 4; nt++) {
                int col = n0 + wn + nt * 16 + lcol;
                int s   = m0 + wm + mt * 16 + lrow * 4;
                bf16x4 ov = { (bf16)acc[mt][nt][0], (bf16)acc[mt][nt][1],
                              (bf16)acc[mt][nt][2], (bf16)acc[mt][nt][3] };
                *(bf16x4*)(&VTw[(size_t)col * S_LEN + s]) = ov;
            }
    }
}

// ---------------------------------------------------------------------------
// Flash attention r23: 512-thread QUAD-Q block. Merges blocks (pi,p) and
// (pi+1,p) — whose K/V tile sets are near-identical — so 8 waves share one
// K/V staging pipeline: wave-group 0 (waves 0-3) handles q-tiles
// {2a, 63-2a}, group 1 (waves 4-7) handles {2a+1, 62-2a}. Per K/V stage:
// 96 MFMA instead of 48; staging instrs + barriers per unit work halve;
// K/V global reads halve. LDS unchanged (34816B), VGPR/wave unchanged,
// residency 2 blocks x 8 waves = 16 waves/CU (>= today's avg 10).
// Group-1 waves idle at most one tail iteration (actB guard).
// Per-wave loop body = r12-exact (setprio kept: -1us consistent sign).
// ---------------------------------------------------------------------------
__launch_bounds__(512, 4)
__global__ void flash_attn(const bf16* __restrict__ Q, const bf16* __restrict__ K,
                           const bf16* __restrict__ VT,
                           float* __restrict__ O0, float* __restrict__ O1,
                           float* __restrict__ L0, float* __restrict__ L1)
{
    const int h   = blockIdx.y;
    const int a0  = blockIdx.x >> 1;            // 0..15 pair index
    const int a   = ((h >> 3) & 1) ? (15 - a0) : a0;   // per-CU balance remap
    const int p   = blockIdx.x & 1;
    const int tid  = threadIdx.x;               // 0..511
    const int wave = tid >> 6;                  // 0..7
    const int g    = wave >> 2;                 // q-pair group 0/1
    const int w4   = wave & 3;
    const int lane = tid & 63;
    const int lrow = lane >> 4;
    const int lcol = lane & 15;

    const int pi   = 2 * a + g;
    const int qtA  = pi;
    const int qtB  = 63 - pi;
    const int tmax = 63 - 2 * a;                // shared staging span (group0's qtB)

    float* __restrict__ Op = p ? O1 : O0;
    float* __restrict__ Lp = p ? L1 : L0;

    __shared__ __align__(16) bf16 Ks[2][64 * FST];
    __shared__ __align__(16) bf16 Vs[2][64 * FST];

    const int q0A = qtA * 64 + w4 * 16;
    const int q0B = qtB * 64 + w4 * 16;

    const bf16* qpA = Q + (size_t)(q0A + lcol) * DM + h * HD;
    const bf16* qpB = Q + (size_t)(q0B + lcol) * DM + h * HD;
    bf16x8 qfA[2], qfB[2];
    qfA[0] = *(const bf16x8*)(qpA + 0 + lrow * 8);
    qfA[1] = *(const bf16x8*)(qpA + 32 + lrow * 8);
    qfB[0] = *(const bf16x8*)(qpB + 0 + lrow * 8);
    qfB[1] = *(const bf16x8*)(qpB + 32 + lrow * 8);

    float lA = 0.f, lB = 0.f;
    floatx4 oaccA[4], oaccB[4];
    #pragma unroll
    for (int nt = 0; nt < 4; nt++) {
        oaccA[nt] = (floatx4){0.f, 0.f, 0.f, 0.f};
        oaccB[nt] = (floatx4){0.f, 0.f, 0.f, 0.f};
    }

    // staging: 512 threads cover 64 rows x 8 chunks in ONE uint4 each for K,V
    const int  srow = tid >> 3;                 // 0..63
    const int  sch  = (tid & 7) * 8;
    const bf16* kp  = K  + (size_t)srow * DM + h * HD + sch;
    const bf16* vp  = VT + (size_t)(h * HD + srow) * S_LEN + sch;
    const int  wof  = srow * FST + sch;

    {
        uint4 ak = *(const uint4*)(kp + (size_t)p * 64 * DM);
        uint4 av = *(const uint4*)(vp + (size_t)p * 64);
        *(uint4*)(&Ks[0][wof]) = ak;
        *(uint4*)(&Vs[0][wof]) = av;
    }
    __syncthreads();

    uint4 kr0, vr0;
    for (int t = p; t <= tmax; t += 2) {
        const int  cur  = ((t - p) >> 1) & 1;
        const bool more = (t + 2 <= tmax);
        const bool actB = (t <= qtB);           // false only: group1 tail iter
        const bool actA = (t <= qtA);

        if (more) {
            kr0 = *(const uint4*)(kp + (size_t)(t + 2) * 64 * DM);
            vr0 = *(const uint4*)(vp + (size_t)(t + 2) * 64);
        }

        short4v pbA[4], pbB[4];
        if (actB) {
            const bool diagA = (t == qtA);
            const bool diagB = (t == qtB);
            #pragma unroll
            for (int nt = 0; nt < 4; nt++) {
                floatx4 zB = (floatx4){0.f, 0.f, 0.f, 0.f};
                floatx4 zA = (floatx4){0.f, 0.f, 0.f, 0.f};
                __builtin_amdgcn_s_setprio(1);
                #pragma unroll
                for (int ks = 0; ks < 2; ks++) {
                    bf16x8 kf = *(const bf16x8*)(&Ks[cur][(nt * 16 + lcol) * FST + ks * 32 + lrow * 8]);
                    zB = __builtin_amdgcn_mfma_f32_16x16x32_bf16(kf, qfB[ks], zB, 0, 0, 0);
                    if (actA)
                        zA = __builtin_amdgcn_mfma_f32_16x16x32_bf16(kf, qfA[ks], zA, 0, 0, 0);
                }
                __builtin_amdgcn_s_setprio(0);
                if (diagB) {
                    #pragma unroll
                    for (int r = 0; r < 4; r++) {
                        int kg = t * 64 + nt * 16 + lrow * 4 + r;
                        float pr = exp2f(zB[r]);
                        if (kg > q0B + lcol) pr = 0.f;
                        zB[r] = pr; lB += pr;
                    }
                } else {
                    #pragma unroll
                    for (int r = 0; r < 4; r++) {
                        float pr = exp2f(zB[r]);
                        zB[r] = pr; lB += pr;
                    }
                }
                bf16x4 pvB = { (bf16)zB[0], (bf16)zB[1], (bf16)zB[2], (bf16)zB[3] };
                pbB[nt] = __builtin_bit_cast(short4v, pvB);
                if (actA) {
                    if (diagA) {
                        #pragma unroll
                        for (int r = 0; r < 4; r++) {
                            int kg = t * 64 + nt * 16 + lrow * 4 + r;
                            float pr = exp2f(zA[r]);
                            if (kg > q0A + lcol) pr = 0.f;
                            zA[r] = pr; lA += pr;
                        }
                    } else {
                        #pragma unroll
                        for (int r = 0; r < 4; r++) {
                            float pr = exp2f(zA[r]);
                            zA[r] = pr; lA += pr;
                        }
                    }
                    bf16x4 pvA = { (bf16)zA[0], (bf16)zA[1], (bf16)zA[2], (bf16)zA[3] };
                    pbA[nt] = __builtin_bit_cast(short4v, pvA);
                }
            }

            __builtin_amdgcn_s_setprio(1);
            #pragma unroll
            for (int nt = 0; nt < 4; nt++)
                #pragma unroll
                for (int kt = 0; kt < 4; kt++) {
                    bf16x4 va = *(const bf16x4*)(&Vs[cur][(nt * 16 + lcol) * FST + kt * 16 + lrow * 4]);
                    short4v vas = __builtin_bit_cast(short4v, va);
                    oaccB[nt] = __builtin_amdgcn_mfma_f32_16x16x16bf16_1k(vas, pbB[kt], oaccB[nt], 0, 0, 0);
                    if (actA)
                        oaccA[nt] = __builtin_amdgcn_mfma_f32_16x16x16bf16_1k(vas, pbA[kt], oaccA[nt], 0, 0, 0);
                }
            __builtin_amdgcn_s_setprio(0);
        }

        if (more) {
            int nxt = cur ^ 1;
            *(uint4*)(&Ks[nxt][wof]) = kr0;
            *(uint4*)(&Vs[nxt][wof]) = vr0;
        }
        __syncthreads();
    }

    lA += __shfl_xor(lA, 16, 64);
    lA += __shfl_xor(lA, 32, 64);
    lB += __shfl_xor(lB, 16, 64);
    lB += __shfl_xor(lB, 32, 64);
    if (lrow == 0) {
        Lp[h * S_LEN + q0A + lcol] = lA;
        Lp[h * S_LEN + q0B + lcol] = lB;
    }
    #pragma unroll
    for (int nt = 0; nt < 4; nt++) {
        *(floatx4*)(&Op[(size_t)(q0A + lcol) * DM + h * HD + nt * 16 + lrow * 4]) = oaccA[nt];
        *(floatx4*)(&Op[(size_t)(q0B + lcol) * DM + h * HD + nt * 16 + lrow * 4]) = oaccB[nt];
    }
}

// ---------------------------------------------------------------------------
// Combine: Aw = (O0 + O1) / (l0 + l1), fp32 -> bf16.
// ---------------------------------------------------------------------------
__global__ void combine_kernel(const float* __restrict__ O0, const float* __restrict__ O1,
                               const float* __restrict__ L0, const float* __restrict__ L1,
                               bf16* __restrict__ Aw)
{
    int i4 = (blockIdx.x * 256 + threadIdx.x) * 4;   // 4M elems
    int q = i4 >> 10;
    int c = i4 & 1023;
    int h = c >> 6;
    float rl = 1.f / (L0[h * S_LEN + q] + L1[h * S_LEN + q]);
    float4 a = *(const float4*)(O0 + i4);
    float4 b = *(const float4*)(O1 + i4);
    bf16x4 o = { (bf16)((a.x + b.x) * rl), (bf16)((a.y + b.y) * rl),
                 (bf16)((a.z + b.z) * rl), (bf16)((a.w + b.w) * rl) };
    *(bf16x4*)(&Aw[i4]) = o;
}

// ---------------------------------------------------------------------------
// Output projection (r11-exact): dbuf + T2 swizzle + XCD-chunk.
// ---------------------------------------------------------------------------
__launch_bounds__(256)
__global__ void gemm_out(const bf16* __restrict__ A, const bf16* __restrict__ B,
                         float* __restrict__ out)
{
    const int bid = blockIdx.x;                 // 0..511, 1-D launch
    const int swz = (bid & 7) * 64 + (bid >> 3);
    const int m0  = (swz >> 3) * 64;
    const int n0  = (swz & 7) * 128;

    const int tid  = threadIdx.x;
    const int wave = tid >> 6;
    const int lane = tid & 63;
    const int wm   = (wave >> 1) * 32;
    const int wn   = (wave & 1) * 64;
    const int lrow = lane >> 4;
    const int lcol = lane & 15;

    __shared__ __align__(16) bf16 As[2][64 * 64];
    __shared__ __align__(16) bf16 Bs[2][128 * 64];

    floatx4 acc[2][4];
    #pragma unroll
    for (int i = 0; i < 2; i++)
        #pragma unroll
        for (int j = 0; j < 4; j++) acc[i][j] = (floatx4){0.f, 0.f, 0.f, 0.f};

    const int swc = (((lane & 7) ^ ((lane >> 3) & 7))) * 8;
    const bf16* ga0 = A + (size_t)(m0 + wave * 16 + (lane >> 3)) * GK + swc;
    const bf16* gb0 = B + (size_t)(n0 + wave * 32 + (lane >> 3)) * GK + swc;
    const int kof0 = ((0 + lrow) ^ (lcol & 7)) * 8;
    const int kof1 = ((4 + lrow) ^ (lcol & 7)) * 8;

    #pragma unroll
    for (int i = 0; i < 2; i++)
        GLDS16(ga0 + (size_t)i * 8 * GK, &As[0][(wave * 16 + i * 8) * 64]);
    #pragma unroll
    for (int i = 0; i < 4; i++)
        GLDS16(gb0 + (size_t)i * 8 * GK, &Bs[0][(wave * 32 + i * 8) * 64]);
    __syncthreads();

    int cur = 0;
    for (int kt = 0; kt < GK; kt += 64) {
        if (kt + 64 < GK) {
            #pragma unroll
            for (int i = 0; i < 2; i++)
                GLDS16(ga0 + kt + 64 + (size_t)i * 8 * GK, &As[cur ^ 1][(wave * 16 + i * 8) * 64]);
            #pragma unroll
            for (int i = 0; i < 4; i++)
                GLDS16(gb0 + kt + 64 + (size_t)i * 8 * GK, &Bs[cur ^ 1][(wave * 32 + i * 8) * 64]);
        }
        #pragma unroll
        for (int ks = 0; ks < 2; ks++) {
            const int ko = ks ? kof1 : kof0;
            bf16x8 af[2], bfr[4];
            #pragma unroll
            for (int t = 0; t < 2; t++)
                af[t]  = *(const bf16x8*)(&As[cur][(wm + t * 16 + lcol) * 64 + ko]);
            #pragma unroll
            for (int t = 0; t < 4; t++)
                bfr[t] = *(const bf16x8*)(&Bs[cur][(wn + t * 16 + lcol) * 64 + ko]);
            #pragma unroll
            for (int mt = 0; mt < 2; mt++)
                #pragma unroll
                for (int nt = 0; nt < 4; nt++)
                    acc[mt][nt] = __builtin_amdgcn_mfma_f32_16x16x32_bf16(af[mt], bfr[nt], acc[mt][nt], 0, 0, 0);
        }
        __syncthreads();
        cur ^= 1;
    }

    #pragma unroll
    for (int mt = 0; mt < 2; mt++)
        #pragma unroll
        for (int nt = 0; nt < 4; nt++)
            #pragma unroll
            for (int r = 0; r < 4; r++) {
                int row = m0 + wm + mt * 16 + lrow * 4 + r;
                int col = n0 + wn + nt * 16 + lcol;
                out[(size_t)row * GN + col] = acc[mt][nt][r];
            }
}

// ---------------------------------------------------------------------------
extern "C" void kernel_launch(void* const* d_in, const int* in_sizes, int n_in,
                              void* d_out, int out_size, void* d_ws, size_t ws_size,
                              hipStream_t stream) {
    const float* x    = (const float*)d_in[0];
    const float* cosp = (const float*)d_in[1];
    const float* sinp = (const float*)d_in[2];
    const float* wq   = (const float*)d_in[4];
    const float* wk   = (const float*)d_in[5];
    const float* wv   = (const float*)d_in[6];
    const float* wo   = (const float*)d_in[7];
    float* out = (float*)d_out;

    const size_t SD = (size_t)S_LEN * DM;   // 4M elems
    const size_t DD = (size_t)DM * DM;      // 1M elems
    bf16* xb  = (bf16*)d_ws;                // 4M bf16
    bf16* wqb = xb + SD;
    bf16* wkb = wqb + DD;
    bf16* wvb = wkb + DD;
    bf16* wob = wvb + DD;
    bf16* Qw  = wob + DD;                   // 4M bf16 each
    bf16* Kw  = Qw + SD;
    bf16* VTw = Kw + SD;
    bf16* Aw  = VTw + SD;
    float* O0f = (float*)(Aw + SD);         // 4M fp32 each
    float* O1f = O0f + SD;
    float* L0f = O1f + SD;                  // 64K fp32 each
    float* L1f = L0f + (size_t)S_LEN * NH;

    // 1) fp32 -> bf16 (x + 4 weights)
    cvt_bf16<<<8192, 256, 0, stream>>>(x, wq, wk, wv, wo, xb);
    // 2) QKV projections + RoPE(+scale) + V-transpose (1buf+swz, XCD-chunked)
    gemm_qkv<<<1536, 256, 0, stream>>>(
        xb, wqb, wkb, wvb, cosp, sinp, Qw, Kw, VTw);
    // 3) flash attention (quad-q 512-thread blocks, parity-split partials)
    flash_attn<<<dim3(32, NH), 512, 0, stream>>>(Qw, Kw, VTw, O0f, O1f, L0f, L1f);
    // 4) combine partials -> bf16 Aw
    combine_kernel<<<S_LEN * DM / 1024, 256, 0, stream>>>(O0f, O1f, L0f, L1f, Aw);
    // 5) output projection (dbuf+swz, XCD-chunked)
    gemm_out<<<512, 256, 0, stream>>>(Aw, wob, out);
}

// Round 14
// 268.291 us; speedup vs baseline: 1.0318x; 1.0154x over previous
//
#include <hip/hip_runtime.h>
#include <hip/hip_bf16.h>
#include <math.h>

typedef __bf16 bf16;
typedef __bf16 bf16x4 __attribute__((ext_vector_type(4)));
typedef __bf16 bf16x8 __attribute__((ext_vector_type(8)));
typedef float floatx4 __attribute__((ext_vector_type(4)));
typedef short short4v __attribute__((ext_vector_type(4)));

#define S_LEN 4096
#define DM 1024
#define NH 16
#define HD 64

#define GM 4096
#define GN 1024
#define GK 1024
#define FST 68     // flash LDS row stride (r0-exact)

// softmax scale folded into Q at projection: 1/sqrt(64) * log2(e)
#define QSCALE 0.18033688011112042f

// async global->LDS, 16B per lane; lds base wave-uniform (m97/m104)
#define GLDS16(gp, lp) __builtin_amdgcn_global_load_lds( \
    (const __attribute__((address_space(1))) void*)(gp), \
    (__attribute__((address_space(3))) void*)(lp), 16, 0, 0)

// ---------------------------------------------------------------------------
// fp32 -> bf16: x (4M) + wq/wk/wv/wo (1M each) into contiguous ws.
// ---------------------------------------------------------------------------
__global__ void cvt_bf16(const float* __restrict__ x,  const float* __restrict__ wq,
                         const float* __restrict__ wk, const float* __restrict__ wv,
                         const float* __restrict__ wo, bf16* __restrict__ dst)
{
    size_t i4 = ((size_t)blockIdx.x * 256 + threadIdx.x) * 4;   // 8M elems total
    const float* src; size_t off;
    const size_t M1 = (size_t)1 << 20;
    if      (i4 < 4 * M1) { src = x;  off = i4;          }
    else if (i4 < 5 * M1) { src = wq; off = i4 - 4 * M1; }
    else if (i4 < 6 * M1) { src = wk; off = i4 - 5 * M1; }
    else if (i4 < 7 * M1) { src = wv; off = i4 - 6 * M1; }
    else                  { src = wo; off = i4 - 7 * M1; }
    float4 v = *(const float4*)(src + off);
    bf16x4 o = { (bf16)v.x, (bf16)v.y, (bf16)v.z, (bf16)v.w };
    *(bf16x4*)(&dst[i4]) = o;
}

// ---------------------------------------------------------------------------
// Fused QKV GEMM r24: 64x256 tile, 512 threads (2x4 waves), continuing the
// measured wide-N trend (r9: 64x128 beat 128x128). Per iter: 5 GLDS16/thread
// for 16384 outputs vs 6/256thr for 8192 — stage instrs + L2 requests per
// output HALVE at unchanged per-wave MFMA:ds_read density. LDS 40KB ->
// 3 blocks/CU = 24 waves/CU (same as r11's 6x4). 1buf + T2 swizzle kept.
// A-stage: wave w covers rows 8w..8w+7 in ONE GLDS16 (lane->dest linear,
// wave-uniform base rule). XCD-chunk: 768 % 8 == 0, bijective.
// Epilogue per z: z=0 Q: RoPE * QSCALE; z=1 K: RoPE; z=2 V: transposed store
// (wn stays a multiple of 64 so freq-index math is unchanged).
// ---------------------------------------------------------------------------
__launch_bounds__(512)
__global__ void gemm_qkv(const bf16* __restrict__ A,
                         const bf16* __restrict__ B0, const bf16* __restrict__ B1,
                         const bf16* __restrict__ B2,
                         const float* __restrict__ cosp, const float* __restrict__ sinp,
                         bf16* __restrict__ Qw, bf16* __restrict__ Kw,
                         bf16* __restrict__ VTw)
{
    const int bid = blockIdx.x;                 // 0..767, 1-D launch
    const int swz = (bid & 7) * 96 + (bid >> 3);
    const int bz  = swz >> 8;                   // slice: 256 blocks each
    const int rem = swz & 255;
    const int m0  = (rem >> 2) * 64;            // 64 M-tiles
    const int n0  = (rem & 3) * 256;            // 4 N-tiles
    const bf16* __restrict__ B = (bz == 0) ? B0 : (bz == 1 ? B1 : B2);

    const int tid  = threadIdx.x;               // 0..511
    const int wave = tid >> 6;                  // 0..7
    const int lane = tid & 63;
    const int wm   = (wave >> 2) * 32;          // 0,32
    const int wn   = (wave & 3) * 64;           // 0,64,128,192
    const int lrow = lane >> 4;
    const int lcol = lane & 15;

    __shared__ __align__(16) bf16 As[64 * 64];      //  8KB
    __shared__ __align__(16) bf16 Bs[256 * 64];     // 32KB

    floatx4 acc[2][4];
    #pragma unroll
    for (int i = 0; i < 2; i++)
        #pragma unroll
        for (int j = 0; j < 4; j++) acc[i][j] = (floatx4){0.f, 0.f, 0.f, 0.f};

    // pre-swizzled global source chunk (write side of T2)
    const int swc = (((lane & 7) ^ ((lane >> 3) & 7))) * 8;
    const bf16* ga0 = A + (size_t)(m0 + wave * 8  + (lane >> 3)) * GK + swc;
    const bf16* gb0 = B + (size_t)(n0 + wave * 32 + (lane >> 3)) * GK + swc;
    bf16* la = &As[(wave * 8) * 64];
    bf16* lb = &Bs[(wave * 32) * 64];
    // swizzled read offsets (read side of T2), lane-constant
    const int kof0 = ((0 + lrow) ^ (lcol & 7)) * 8;
    const int kof1 = ((4 + lrow) ^ (lcol & 7)) * 8;

    for (int kt = 0; kt < GK; kt += 64) {
        GLDS16(ga0 + kt, la);                       // A: 1 instr/thread
        #pragma unroll
        for (int i = 0; i < 4; i++)                 // B: 4 instr/thread
            GLDS16(gb0 + kt + (size_t)i * 8 * GK, lb + i * 8 * 64);
        __syncthreads();
        #pragma unroll
        for (int ks = 0; ks < 2; ks++) {
            const int ko = ks ? kof1 : kof0;
            bf16x8 af[2], bfr[4];
            #pragma unroll
            for (int t = 0; t < 2; t++)
                af[t]  = *(const bf16x8*)(&As[(wm + t * 16 + lcol) * 64 + ko]);
            #pragma unroll
            for (int t = 0; t < 4; t++)
                bfr[t] = *(const bf16x8*)(&Bs[(wn + t * 16 + lcol) * 64 + ko]);
            #pragma unroll
            for (int mt = 0; mt < 2; mt++)
                #pragma unroll
                for (int nt = 0; nt < 4; nt++)
                    acc[mt][nt] = __builtin_amdgcn_mfma_f32_16x16x32_bf16(af[mt], bfr[nt], acc[mt][nt], 0, 0, 0);
        }
        __syncthreads();
    }

    if (bz < 2) {
        bf16* __restrict__ C = bz ? Kw : Qw;
        const float qs = (bz == 0) ? QSCALE : 1.0f;
        const bool odd = (lcol & 1);
        #pragma unroll
        for (int mt = 0; mt < 2; mt++)
            #pragma unroll
            for (int nt = 0; nt < 4; nt++) {
                int i = (nt * 16 + lcol) >> 1;   // freq index 0..31 (cols repeat per head)
                #pragma unroll
                for (int r = 0; r < 4; r++) {
                    float v  = acc[mt][nt][r];
                    float pv = __shfl_xor(v, 1, 64);
                    int s = m0 + wm + mt * 16 + lrow * 4 + r;
                    float c  = cosp[s * 32 + i];
                    float sn = sinp[s * 32 + i];
                    float ov = odd ? (pv * sn + v * c) : (v * c - pv * sn);
                    C[(size_t)s * GN + n0 + wn + nt * 16 + lcol] = (bf16)(ov * qs);
                }
            }
    } else {
        #pragma unroll
        for (int mt = 0; mt < 2; mt++)
            #pragma unroll
            for (int nt = 0; nt < 4; nt++) {
                int col = n0 + wn + nt * 16 + lcol;
                int s   = m0 + wm + mt * 16 + lrow * 4;
                bf16x4 ov = { (bf16)acc[mt][nt][0], (bf16)acc[mt][nt][1],
                              (bf16)acc[mt][nt][2], (bf16)acc[mt][nt][3] };
                *(bf16x4*)(&VTw[(size_t)col * S_LEN + s]) = ov;
            }
    }
}

// ---------------------------------------------------------------------------
// Flash attention (r13-exact quad-q): 512-thread block, 8 waves share one
// K/V staging pipeline; group 0 handles {2a, 63-2a}, group 1 {2a+1, 62-2a}.
// Combined issue util ~84% (VALU 50 + MFMA 34) — near structure ceiling.
// ---------------------------------------------------------------------------
__launch_bounds__(512, 4)
__global__ void flash_attn(const bf16* __restrict__ Q, const bf16* __restrict__ K,
                           const bf16* __restrict__ VT,
                           float* __restrict__ O0, float* __restrict__ O1,
                           float* __restrict__ L0, float* __restrict__ L1)
{
    const int h   = blockIdx.y;
    const int a0  = blockIdx.x >> 1;            // 0..15 pair index
    const int a   = ((h >> 3) & 1) ? (15 - a0) : a0;   // per-CU balance remap
    const int p   = blockIdx.x & 1;
    const int tid  = threadIdx.x;               // 0..511
    const int wave = tid >> 6;                  // 0..7
    const int g    = wave >> 2;                 // q-pair group 0/1
    const int w4   = wave & 3;
    const int lane = tid & 63;
    const int lrow = lane >> 4;
    const int lcol = lane & 15;

    const int pi   = 2 * a + g;
    const int qtA  = pi;
    const int qtB  = 63 - pi;
    const int tmax = 63 - 2 * a;                // shared staging span (group0's qtB)

    float* __restrict__ Op = p ? O1 : O0;
    float* __restrict__ Lp = p ? L1 : L0;

    __shared__ __align__(16) bf16 Ks[2][64 * FST];
    __shared__ __align__(16) bf16 Vs[2][64 * FST];

    const int q0A = qtA * 64 + w4 * 16;
    const int q0B = qtB * 64 + w4 * 16;

    const bf16* qpA = Q + (size_t)(q0A + lcol) * DM + h * HD;
    const bf16* qpB = Q + (size_t)(q0B + lcol) * DM + h * HD;
    bf16x8 qfA[2], qfB[2];
    qfA[0] = *(const bf16x8*)(qpA + 0 + lrow * 8);
    qfA[1] = *(const bf16x8*)(qpA + 32 + lrow * 8);
    qfB[0] = *(const bf16x8*)(qpB + 0 + lrow * 8);
    qfB[1] = *(const bf16x8*)(qpB + 32 + lrow * 8);

    float lA = 0.f, lB = 0.f;
    floatx4 oaccA[4], oaccB[4];
    #pragma unroll
    for (int nt = 0; nt < 4; nt++) {
        oaccA[nt] = (floatx4){0.f, 0.f, 0.f, 0.f};
        oaccB[nt] = (floatx4){0.f, 0.f, 0.f, 0.f};
    }

    // staging: 512 threads cover 64 rows x 8 chunks in ONE uint4 each for K,V
    const int  srow = tid >> 3;                 // 0..63
    const int  sch  = (tid & 7) * 8;
    const bf16* kp  = K  + (size_t)srow * DM + h * HD + sch;
    const bf16* vp  = VT + (size_t)(h * HD + srow) * S_LEN + sch;
    const int  wof  = srow * FST + sch;

    {
        uint4 ak = *(const uint4*)(kp + (size_t)p * 64 * DM);
        uint4 av = *(const uint4*)(vp + (size_t)p * 64);
        *(uint4*)(&Ks[0][wof]) = ak;
        *(uint4*)(&Vs[0][wof]) = av;
    }
    __syncthreads();

    uint4 kr0, vr0;
    for (int t = p; t <= tmax; t += 2) {
        const int  cur  = ((t - p) >> 1) & 1;
        const bool more = (t + 2 <= tmax);
        const bool actB = (t <= qtB);           // false only: group1 tail iter
        const bool actA = (t <= qtA);

        if (more) {
            kr0 = *(const uint4*)(kp + (size_t)(t + 2) * 64 * DM);
            vr0 = *(const uint4*)(vp + (size_t)(t + 2) * 64);
        }

        short4v pbA[4], pbB[4];
        if (actB) {
            const bool diagA = (t == qtA);
            const bool diagB = (t == qtB);
            #pragma unroll
            for (int nt = 0; nt < 4; nt++) {
                floatx4 zB = (floatx4){0.f, 0.f, 0.f, 0.f};
                floatx4 zA = (floatx4){0.f, 0.f, 0.f, 0.f};
                __builtin_amdgcn_s_setprio(1);
                #pragma unroll
                for (int ks = 0; ks < 2; ks++) {
                    bf16x8 kf = *(const bf16x8*)(&Ks[cur][(nt * 16 + lcol) * FST + ks * 32 + lrow * 8]);
                    zB = __builtin_amdgcn_mfma_f32_16x16x32_bf16(kf, qfB[ks], zB, 0, 0, 0);
                    if (actA)
                        zA = __builtin_amdgcn_mfma_f32_16x16x32_bf16(kf, qfA[ks], zA, 0, 0, 0);
                }
                __builtin_amdgcn_s_setprio(0);
                if (diagB) {
                    #pragma unroll
                    for (int r = 0; r < 4; r++) {
                        int kg = t * 64 + nt * 16 + lrow * 4 + r;
                        float pr = exp2f(zB[r]);
                        if (kg > q0B + lcol) pr = 0.f;
                        zB[r] = pr; lB += pr;
                    }
                } else {
                    #pragma unroll
                    for (int r = 0; r < 4; r++) {
                        float pr = exp2f(zB[r]);
                        zB[r] = pr; lB += pr;
                    }
                }
                bf16x4 pvB = { (bf16)zB[0], (bf16)zB[1], (bf16)zB[2], (bf16)zB[3] };
                pbB[nt] = __builtin_bit_cast(short4v, pvB);
                if (actA) {
                    if (diagA) {
                        #pragma unroll
                        for (int r = 0; r < 4; r++) {
                            int kg = t * 64 + nt * 16 + lrow * 4 + r;
                            float pr = exp2f(zA[r]);
                            if (kg > q0A + lcol) pr = 0.f;
                            zA[r] = pr; lA += pr;
                        }
                    } else {
                        #pragma unroll
                        for (int r = 0; r < 4; r++) {
                            float pr = exp2f(zA[r]);
                            zA[r] = pr; lA += pr;
                        }
                    }
                    bf16x4 pvA = { (bf16)zA[0], (bf16)zA[1], (bf16)zA[2], (bf16)zA[3] };
                    pbA[nt] = __builtin_bit_cast(short4v, pvA);
                }
            }

            __builtin_amdgcn_s_setprio(1);
            #pragma unroll
            for (int nt = 0; nt < 4; nt++)
                #pragma unroll
                for (int kt = 0; kt < 4; kt++) {
                    bf16x4 va = *(const bf16x4*)(&Vs[cur][(nt * 16 + lcol) * FST + kt * 16 + lrow * 4]);
                    short4v vas = __builtin_bit_cast(short4v, va);
                    oaccB[nt] = __builtin_amdgcn_mfma_f32_16x16x16bf16_1k(vas, pbB[kt], oaccB[nt], 0, 0, 0);
                    if (actA)
                        oaccA[nt] = __builtin_amdgcn_mfma_f32_16x16x16bf16_1k(vas, pbA[kt], oaccA[nt], 0, 0, 0);
                }
            __builtin_amdgcn_s_setprio(0);
        }

        if (more) {
            int nxt = cur ^ 1;
            *(uint4*)(&Ks[nxt][wof]) = kr0;
            *(uint4*)(&Vs[nxt][wof]) = vr0;
        }
        __syncthreads();
    }

    lA += __shfl_xor(lA, 16, 64);
    lA += __shfl_xor(lA, 32, 64);
    lB += __shfl_xor(lB, 16, 64);
    lB += __shfl_xor(lB, 32, 64);
    if (lrow == 0) {
        Lp[h * S_LEN + q0A + lcol] = lA;
        Lp[h * S_LEN + q0B + lcol] = lB;
    }
    #pragma unroll
    for (int nt = 0; nt < 4; nt++) {
        *(floatx4*)(&Op[(size_t)(q0A + lcol) * DM + h * HD + nt * 16 + lrow * 4]) = oaccA[nt];
        *(floatx4*)(&Op[(size_t)(q0B + lcol) * DM + h * HD + nt * 16 + lrow * 4]) = oaccB[nt];
    }
}

// ---------------------------------------------------------------------------
// Combine: Aw = (O0 + O1) / (l0 + l1), fp32 -> bf16.
// ---------------------------------------------------------------------------
__global__ void combine_kernel(const float* __restrict__ O0, const float* __restrict__ O1,
                               const float* __restrict__ L0, const float* __restrict__ L1,
                               bf16* __restrict__ Aw)
{
    int i4 = (blockIdx.x * 256 + threadIdx.x) * 4;   // 4M elems
    int q = i4 >> 10;
    int c = i4 & 1023;
    int h = c >> 6;
    float rl = 1.f / (L0[h * S_LEN + q] + L1[h * S_LEN + q]);
    float4 a = *(const float4*)(O0 + i4);
    float4 b = *(const float4*)(O1 + i4);
    bf16x4 o = { (bf16)((a.x + b.x) * rl), (bf16)((a.y + b.y) * rl),
                 (bf16)((a.z + b.z) * rl), (bf16)((a.w + b.w) * rl) };
    *(bf16x4*)(&Aw[i4]) = o;
}

// ---------------------------------------------------------------------------
// Output projection (r11-exact): dbuf + T2 swizzle + XCD-chunk.
// (64x256 would shrink the grid to 1 block/CU — keep 64x128.)
// ---------------------------------------------------------------------------
__launch_bounds__(256)
__global__ void gemm_out(const bf16* __restrict__ A, const bf16* __restrict__ B,
                         float* __restrict__ out)
{
    const int bid = blockIdx.x;                 // 0..511, 1-D launch
    const int swz = (bid & 7) * 64 + (bid >> 3);
    const int m0  = (swz >> 3) * 64;
    const int n0  = (swz & 7) * 128;

    const int tid  = threadIdx.x;
    const int wave = tid >> 6;
    const int lane = tid & 63;
    const int wm   = (wave >> 1) * 32;
    const int wn   = (wave & 1) * 64;
    const int lrow = lane >> 4;
    const int lcol = lane & 15;

    __shared__ __align__(16) bf16 As[2][64 * 64];
    __shared__ __align__(16) bf16 Bs[2][128 * 64];

    floatx4 acc[2][4];
    #pragma unroll
    for (int i = 0; i < 2; i++)
        #pragma unroll
        for (int j = 0; j < 4; j++) acc[i][j] = (floatx4){0.f, 0.f, 0.f, 0.f};

    const int swc = (((lane & 7) ^ ((lane >> 3) & 7))) * 8;
    const bf16* ga0 = A + (size_t)(m0 + wave * 16 + (lane >> 3)) * GK + swc;
    const bf16* gb0 = B + (size_t)(n0 + wave * 32 + (lane >> 3)) * GK + swc;
    const int kof0 = ((0 + lrow) ^ (lcol & 7)) * 8;
    const int kof1 = ((4 + lrow) ^ (lcol & 7)) * 8;

    #pragma unroll
    for (int i = 0; i < 2; i++)
        GLDS16(ga0 + (size_t)i * 8 * GK, &As[0][(wave * 16 + i * 8) * 64]);
    #pragma unroll
    for (int i = 0; i < 4; i++)
        GLDS16(gb0 + (size_t)i * 8 * GK, &Bs[0][(wave * 32 + i * 8) * 64]);
    __syncthreads();

    int cur = 0;
    for (int kt = 0; kt < GK; kt += 64) {
        if (kt + 64 < GK) {
            #pragma unroll
            for (int i = 0; i < 2; i++)
                GLDS16(ga0 + kt + 64 + (size_t)i * 8 * GK, &As[cur ^ 1][(wave * 16 + i * 8) * 64]);
            #pragma unroll
            for (int i = 0; i < 4; i++)
                GLDS16(gb0 + kt + 64 + (size_t)i * 8 * GK, &Bs[cur ^ 1][(wave * 32 + i * 8) * 64]);
        }
        #pragma unroll
        for (int ks = 0; ks < 2; ks++) {
            const int ko = ks ? kof1 : kof0;
            bf16x8 af[2], bfr[4];
            #pragma unroll
            for (int t = 0; t < 2; t++)
                af[t]  = *(const bf16x8*)(&As[cur][(wm + t * 16 + lcol) * 64 + ko]);
            #pragma unroll
            for (int t = 0; t < 4; t++)
                bfr[t] = *(const bf16x8*)(&Bs[cur][(wn + t * 16 + lcol) * 64 + ko]);
            #pragma unroll
            for (int mt = 0; mt < 2; mt++)
                #pragma unroll
                for (int nt = 0; nt < 4; nt++)
                    acc[mt][nt] = __builtin_amdgcn_mfma_f32_16x16x32_bf16(af[mt], bfr[nt], acc[mt][nt], 0, 0, 0);
        }
        __syncthreads();
        cur ^= 1;
    }

    #pragma unroll
    for (int mt = 0; mt < 2; mt++)
        #pragma unroll
        for (int nt = 0; nt < 4; nt++)
            #pragma unroll
            for (int r = 0; r < 4; r++) {
                int row = m0 + wm + mt * 16 + lrow * 4 + r;
                int col = n0 + wn + nt * 16 + lcol;
                out[(size_t)row * GN + col] = acc[mt][nt][r];
            }
}

// ---------------------------------------------------------------------------
extern "C" void kernel_launch(void* const* d_in, const int* in_sizes, int n_in,
                              void* d_out, int out_size, void* d_ws, size_t ws_size,
                              hipStream_t stream) {
    const float* x    = (const float*)d_in[0];
    const float* cosp = (const float*)d_in[1];
    const float* sinp = (const float*)d_in[2];
    const float* wq   = (const float*)d_in[4];
    const float* wk   = (const float*)d_in[5];
    const float* wv   = (const float*)d_in[6];
    const float* wo   = (const float*)d_in[7];
    float* out = (float*)d_out;

    const size_t SD = (size_t)S_LEN * DM;   // 4M elems
    const size_t DD = (size_t)DM * DM;      // 1M elems
    bf16* xb  = (bf16*)d_ws;                // 4M bf16
    bf16* wqb = xb + SD;
    bf16* wkb = wqb + DD;
    bf16* wvb = wkb + DD;
    bf16* wob = wvb + DD;
    bf16* Qw  = wob + DD;                   // 4M bf16 each
    bf16* Kw  = Qw + SD;
    bf16* VTw = Kw + SD;
    bf16* Aw  = VTw + SD;
    float* O0f = (float*)(Aw + SD);         // 4M fp32 each
    float* O1f = O0f + SD;
    float* L0f = O1f + SD;                  // 64K fp32 each
    float* L1f = L0f + (size_t)S_LEN * NH;

    // 1) fp32 -> bf16 (x + 4 weights)
    cvt_bf16<<<8192, 256, 0, stream>>>(x, wq, wk, wv, wo, xb);
    // 2) QKV projections + RoPE(+scale) + V-transpose (64x256, 512thr, XCD)
    gemm_qkv<<<768, 512, 0, stream>>>(
        xb, wqb, wkb, wvb, cosp, sinp, Qw, Kw, VTw);
    // 3) flash attention (quad-q 512-thread blocks, parity-split partials)
    flash_attn<<<dim3(32, NH), 512, 0, stream>>>(Qw, Kw, VTw, O0f, O1f, L0f, L1f);
    // 4) combine partials -> bf16 Aw
    combine_kernel<<<S_LEN * DM / 1024, 256, 0, stream>>>(O0f, O1f, L0f, L1f, Aw);
    // 5) output projection (dbuf+swz, XCD-chunked)
    gemm_out<<<512, 256, 0, stream>>>(Aw, wob, out);
}